// Round 7
// baseline (117.619 us; speedup 1.0000x reference)
//
#include <hip/hip_runtime.h>
#include <hip/hip_bf16.h>
#include <math.h>

typedef __hip_bfloat16 bf16;
typedef __attribute__((ext_vector_type(8))) short bf16x8;
typedef __attribute__((ext_vector_type(4))) float f32x4;
typedef __attribute__((ext_vector_type(16))) float f32x16;

#define DI static __device__ __forceinline__

constexpr int NB = 1024;   // batch
constexpr int ND = 1024;   // latent dim (= out dim)
constexpr int NP = 16;     // parts
constexpr int BKT = 32;    // K-step per tile
constexpr int NKT = ND / BKT;  // 32

DI float gelu_exact(float x) {
    return 0.5f * x * (1.0f + erff(x * 0.70710678118654752f));
}

DI ushort bf16_bits(float f) {
    bf16 h = __float2bfloat16(f);
    return *reinterpret_cast<ushort*>(&h);
}

// ---------- pack x only: [B,D,P] f32 -> [P][B][D] bf16 via small-LDS transpose ----------
// One block = (b, quarter of D): 256 d x 16 p = 16 KB read. LDS 8.4 KB.
__global__ __launch_bounds__(256) void pack_kernel(const float* __restrict__ x,
                                                   bf16* __restrict__ xp) {
    __shared__ ushort lds[16][264];              // 516B rows -> 2-way banks (free)
    const int t = threadIdx.x;
    const int b = blockIdx.x >> 2;
    const int q = blockIdx.x & 3;                // d-quarter: d0 = q*256
    const float* xb = x + ((size_t)b * ND + q * 256) * NP;
    float4 va[2], vb[2];
#pragma unroll
    for (int it = 0; it < 2; ++it) {
        const int u  = it * 256 + t;             // 0..511
        const int dh = u >> 2;                   // d-pair 0..127
        const int p0 = (u & 3) * 4;
        va[it] = *reinterpret_cast<const float4*>(&xb[(size_t)(dh * 2)     * NP + p0]);
        vb[it] = *reinterpret_cast<const float4*>(&xb[(size_t)(dh * 2 + 1) * NP + p0]);
    }
#pragma unroll
    for (int it = 0; it < 2; ++it) {
        const int u  = it * 256 + t;
        const int dh = u >> 2;
        const int p0 = (u & 3) * 4;
        const float a0[4] = { va[it].x, va[it].y, va[it].z, va[it].w };
        const float a1[4] = { vb[it].x, vb[it].y, vb[it].z, vb[it].w };
#pragma unroll
        for (int k = 0; k < 4; ++k) {
            const uint packed = (uint)bf16_bits(a0[k]) | ((uint)bf16_bits(a1[k]) << 16);
            *reinterpret_cast<uint*>(&lds[p0 + k][dh * 2]) = packed;
        }
    }
    __syncthreads();
    const int p = t >> 4, j = t & 15;
    bf16* dst = xp + (size_t)p * (NB * ND) + (size_t)b * ND + q * 256;
#pragma unroll
    for (int it = 0; it < 2; ++it) {
        const int c = it * 16 + j;               // 0..31 chunks of 8 bf16
        *reinterpret_cast<bf16x8*>(&dst[c * 8]) =
            *reinterpret_cast<const bf16x8*>(&lds[p][c * 8]);
    }
}

// ---------- grouped GEMM: 256x256 tile, 8 waves, 32x32x16 MFMA ----------
// A (xp, bf16) staged via global_load_lds (linear dest + inverse-swizzled src).
// B staged DIRECTLY from W f32: coalesced float4 reg-loads issued early,
// cvt + swizzled ds_write late (T14). Triple-buffered LDS, counted vmcnt(6).
__global__ __launch_bounds__(512, 1) void gemm8_kernel(const bf16* __restrict__ xp,
                                                       const float* __restrict__ wsrc,
                                                       bf16* __restrict__ y) {
    __shared__ bf16 As[3][256 * BKT];
    __shared__ bf16 Bs[3][256 * BKT];
    const int i = blockIdx.x;
    const int p    = ((i & 7) << 1) | ((i >> 3) & 1);   // part -> XCD i&7
    const int tile = i >> 4;                             // 0..15
    const int bt = (tile >> 2) * 256;
    const int ot = (tile & 3) * 256;
    const bf16*  A  = xp   + (size_t)p * NB * ND;        // [B][D] bf16
    const float* Bm = wsrc + (size_t)p * ND * ND;        // [O][D] f32
    const int t = threadIdx.x;
    const int l = t & 63, w = t >> 6;            // 8 waves
    const int wr = w >> 2, wc = w & 3;           // 2(M) x 4(N): wave tile 128x64
    const int lr32 = l & 31, g2 = l >> 5;        // mfma row / k-half

    f32x16 acc[4][2] = {};                       // 4 m x 2 n of 32x32
    float4 bregA[4], bregB[4];                   // two named in-flight B sets (rule 20)

    const int sA = w * 64 + l;                   // 0..511

    auto issueA = [&](int buf, int kt, int q) {  // q=0,1 ; A half-tile 8KB each
        const int s   = (q * 8 + w) * 64 + l;    // 16B slot 0..1023
        const int row = s >> 2;
        const int cb  = (s & 3) ^ ((row >> 1) & 3);
        const bf16* gsrc = A + (size_t)(bt + row) * ND + kt * BKT + cb * 8;
        bf16* ldst = &As[buf][(q * 8 + w) * 512];
        __builtin_amdgcn_global_load_lds((const __attribute__((address_space(1))) void*)gsrc,
                                         (__attribute__((address_space(3))) void*)ldst, 16, 0, 0);
    };
    // B tile = 256 rows x 32 f32 = 2048 x 16B chunks; load i covers chunks i*512+s:
    // 64 consecutive lanes = 8 full rows, fully contiguous 128B segments.
    auto issueB = [&](int kt, float4 (&r)[4]) {
#pragma unroll
        for (int i2 = 0; i2 < 4; ++i2) {
            const int g   = i2 * 512 + sA;
            const int row = g >> 3, o16 = g & 7;
            r[i2] = *reinterpret_cast<const float4*>(&Bm[(size_t)(ot + row) * ND + kt * BKT + o16 * 4]);
        }
    };
    auto writeB = [&](int buf, const float4 (&r)[4]) {
#pragma unroll
        for (int i2 = 0; i2 < 4; ++i2) {
            const int g   = i2 * 512 + sA;
            const int row = g >> 3, o16 = g & 7;
            const int ch = o16 >> 1, h8 = o16 & 1;
            alignas(8) bf16 tmp[4] = { __float2bfloat16(r[i2].x), __float2bfloat16(r[i2].y),
                                       __float2bfloat16(r[i2].z), __float2bfloat16(r[i2].w) };
            const int slot = row * 4 + (ch ^ ((row >> 1) & 3));
            *reinterpret_cast<uint2*>(&Bs[buf][slot * 8 + h8 * 4]) =
                *reinterpret_cast<const uint2*>(tmp);
        }
    };
    auto readA = [&](int buf, int m, int s) -> bf16x8 {
        const int row  = wr * 128 + m * 32 + lr32;
        const int ch   = s * 2 + g2;
        const int slot = row * 4 + (ch ^ ((row >> 1) & 3));
        return *reinterpret_cast<const bf16x8*>(&As[buf][slot * 8]);
    };
    auto readB = [&](int buf, int n, int s) -> bf16x8 {
        const int row  = wc * 64 + n * 32 + lr32;
        const int ch   = s * 2 + g2;
        const int slot = row * 4 + (ch ^ ((row >> 1) & 3));
        return *reinterpret_cast<const bf16x8*>(&Bs[buf][slot * 8]);
    };

    // prologue: tiles 0 and 1 in flight; finish tile 0's B write. Issue order
    // per tile: B loads (4 vmem) then A gload_lds (2 vmem).
    issueB(0, bregA); issueA(0, 0, 0); issueA(0, 0, 1);
    issueB(1, bregB); issueA(1, 1, 0); issueA(1, 1, 1);
    asm volatile("s_waitcnt vmcnt(6)" ::: "memory");     // tile0 A+B resident
    writeB(0, bregA);
    asm volatile("s_waitcnt lgkmcnt(0)" ::: "memory");
    __builtin_amdgcn_s_barrier();
    __builtin_amdgcn_sched_barrier(0);

#pragma unroll 1
    for (int kt = 0; kt < NKT; ++kt) {
        const int c  = kt % 3;
        const int n1 = (kt + 1) % 3;
        const int s2 = (kt + 2) % 3;
        // ---- phase 0: k-step 0 frags ; issue B loads of tile kt+2 ----
        bf16x8 bfr[2], af[4];
#pragma unroll
        for (int n = 0; n < 2; ++n) bfr[n] = readB(c, n, 0);
#pragma unroll
        for (int m = 0; m < 4; ++m) af[m] = readA(c, m, 0);
        if (kt + 2 < NKT) {
            if ((kt & 1) == 0) issueB(kt + 2, bregA);
            else               issueB(kt + 2, bregB);
        }
        __builtin_amdgcn_s_barrier();
        asm volatile("s_waitcnt lgkmcnt(0)" ::: "memory");
        __builtin_amdgcn_s_setprio(1);
#pragma unroll
        for (int m = 0; m < 4; ++m)
#pragma unroll
            for (int n = 0; n < 2; ++n)
                acc[m][n] = __builtin_amdgcn_mfma_f32_32x32x16_bf16(af[m], bfr[n], acc[m][n], 0, 0, 0);
        __builtin_amdgcn_s_setprio(0);
        __builtin_amdgcn_s_barrier();
        // ---- phase 1: k-step 1 frags ; issue A gload_lds of tile kt+2 ----
#pragma unroll
        for (int n = 0; n < 2; ++n) bfr[n] = readB(c, n, 1);
#pragma unroll
        for (int m = 0; m < 4; ++m) af[m] = readA(c, m, 1);
        if (kt + 2 < NKT) { issueA(s2, kt + 2, 0); issueA(s2, kt + 2, 1); }
        __builtin_amdgcn_s_barrier();
        asm volatile("s_waitcnt lgkmcnt(0)" ::: "memory");
        __builtin_amdgcn_s_setprio(1);
#pragma unroll
        for (int m = 0; m < 4; ++m)
#pragma unroll
            for (int n = 0; n < 2; ++n)
                acc[m][n] = __builtin_amdgcn_mfma_f32_32x32x16_bf16(af[m], bfr[n], acc[m][n], 0, 0, 0);
        __builtin_amdgcn_s_setprio(0);
        // ---- tail: make tile kt+1 fully resident (counted, never 0 mid-loop) ----
        if (kt + 1 < NKT) {
            if (kt + 2 < NKT) asm volatile("s_waitcnt vmcnt(6)" ::: "memory");
            else              asm volatile("s_waitcnt vmcnt(0)" ::: "memory");
            if (((kt + 1) & 1) == 0) writeB(n1, bregA);
            else                     writeB(n1, bregB);
            asm volatile("s_waitcnt lgkmcnt(0)" ::: "memory");
            __builtin_amdgcn_s_barrier();
            __builtin_amdgcn_sched_barrier(0);
        }
    }

    // epilogue: 32x32 C/D layout col = l&31, row = (reg&3) + 8*(reg>>2) + 4*(l>>5)
    bf16* yp = y + (size_t)p * NB * ND;
#pragma unroll
    for (int m = 0; m < 4; ++m) {
#pragma unroll
        for (int n = 0; n < 2; ++n) {
#pragma unroll
            for (int reg = 0; reg < 16; ++reg) {
                const int row = bt + wr * 128 + m * 32 + (reg & 3) + 8 * (reg >> 2) + 4 * g2;
                const int col = ot + wc * 64 + n * 32 + lr32;
                yp[(size_t)row * ND + col] = __float2bfloat16(acc[m][n][reg]);
            }
        }
    }
}

// ---------- y [P][B][O] bf16 (raw) -> out [B][O][P] f32 with exact GELU ----------
__global__ __launch_bounds__(256) void unpack_kernel(const bf16* __restrict__ y,
                                                     float* __restrict__ out) {
    const size_t gidx = (size_t)blockIdx.x * 256 + threadIdx.x;  // (b,o) index
    const size_t o = gidx & 1023;
    const size_t b = gidx >> 10;
    const bf16* yb = y + b * (size_t)ND + o;
    float v[16];
#pragma unroll
    for (int p = 0; p < 16; ++p)
        v[p] = gelu_exact(__bfloat162float(yb[(size_t)p * (NB * ND)]));
    float4* dst = reinterpret_cast<float4*>(out + gidx * NP);
#pragma unroll
    for (int q = 0; q < 4; ++q)
        dst[q] = make_float4(v[q * 4], v[q * 4 + 1], v[q * 4 + 2], v[q * 4 + 3]);
}

// ---------- fallback: pure-f32 tiled GEMM (tiny ws) ----------
__global__ __launch_bounds__(256) void fallback_kernel(const float* __restrict__ x,
                                                       const float* __restrict__ w,
                                                       float* __restrict__ out) {
    __shared__ float As[64][17];
    __shared__ float Bs[64][17];
    const int p = blockIdx.z, bt = blockIdx.y * 64, ot = blockIdx.x * 64;
    const int t = threadIdx.x;
    const int tx = t & 15, ty = t >> 4;
    float acc[4][4] = {};
    for (int k0 = 0; k0 < ND; k0 += 16) {
        __syncthreads();
#pragma unroll
        for (int i = 0; i < 4; ++i) {
            const int idx = i * 256 + t;
            const int r = idx >> 4, k = idx & 15;
            As[r][k] = x[((size_t)(bt + r) * ND + k0 + k) * NP + p];
            Bs[r][k] = w[(size_t)p * ND * ND + (size_t)(ot + r) * ND + k0 + k];
        }
        __syncthreads();
#pragma unroll
        for (int k = 0; k < 16; ++k) {
            float a[4], bb[4];
#pragma unroll
            for (int i = 0; i < 4; ++i) a[i] = As[ty * 4 + i][k];
#pragma unroll
            for (int j = 0; j < 4; ++j) bb[j] = Bs[tx * 4 + j][k];
#pragma unroll
            for (int i = 0; i < 4; ++i)
#pragma unroll
                for (int j = 0; j < 4; ++j) acc[i][j] += a[i] * bb[j];
        }
    }
#pragma unroll
    for (int i = 0; i < 4; ++i)
#pragma unroll
        for (int j = 0; j < 4; ++j)
            out[((size_t)(bt + ty * 4 + i) * ND + (ot + tx * 4 + j)) * NP + p] =
                gelu_exact(acc[i][j]);
}

extern "C" void kernel_launch(void* const* d_in, const int* in_sizes, int n_in,
                              void* d_out, int out_size, void* d_ws, size_t ws_size,
                              hipStream_t stream) {
    const float* x = (const float*)d_in[0];
    const float* w = (const float*)d_in[1];
    float* out = (float*)d_out;

    const size_t nElem  = (size_t)NP * NB * ND;           // 16M
    const size_t xpB    = nElem * sizeof(bf16);           // 32 MiB
    const size_t yB     = nElem * sizeof(bf16);           // 32 MiB

    if (ws_size >= xpB + yB) {
        bf16* xp = (bf16*)d_ws;
        bf16* y  = (bf16*)((char*)d_ws + xpB);
        pack_kernel<<<4096, 256, 0, stream>>>(x, xp);
        gemm8_kernel<<<256, 512, 0, stream>>>(xp, w, y);
        unpack_kernel<<<(int)(NB * ND / 256), 256, 0, stream>>>(y, out);
    } else {
        fallback_kernel<<<dim3(16, 16, 16), 256, 0, stream>>>(x, w, out);
    }
}

// Round 8
// 111.821 us; speedup vs baseline: 1.0518x; 1.0518x over previous
//
#include <hip/hip_runtime.h>
#include <hip/hip_bf16.h>
#include <math.h>

typedef __hip_bfloat16 bf16;
typedef __attribute__((ext_vector_type(8))) short bf16x8;
typedef __attribute__((ext_vector_type(4))) float f32x4;
typedef __attribute__((ext_vector_type(16))) float f32x16;

#define DI static __device__ __forceinline__

constexpr int NB = 1024;   // batch
constexpr int ND = 1024;   // latent dim (= out dim)
constexpr int NP = 16;     // parts
constexpr int BKT = 32;    // K-step per tile
constexpr int NKT = ND / BKT;  // 32

DI float gelu_exact(float x) {
    return 0.5f * x * (1.0f + erff(x * 0.70710678118654752f));
}

DI ushort bf16_bits(float f) {
    bf16 h = __float2bfloat16(f);
    return *reinterpret_cast<ushort*>(&h);
}

// ---------- fused pack, occupancy-first ----------
// blocks [0, 4096): x [B,D,P] f32 -> xp [P][B][D] bf16 via small-LDS transpose.
//   One block = (b, quarter of D): 256 d x 16 p = 16 KB read; LDS 8.4 KB.
// blocks [4096, 8192): W f32 -> wp bf16, 16 floats/thread; instruction-level
//   full-line pattern: load k covers 1 KB contiguous per wave (64 x 16B),
//   store k covers 512B contiguous per wave (64 x 8B).
__global__ __launch_bounds__(256, 8) void pack_kernel(const float* __restrict__ x,
                                                      const float* __restrict__ w,
                                                      bf16* __restrict__ xp,
                                                      bf16* __restrict__ wp) {
    __shared__ ushort lds[16][264];              // 528B rows -> 2-way banks (free)
    const int t = threadIdx.x;
    if (blockIdx.x < 4096) {
        const int b = blockIdx.x >> 2;
        const int q = blockIdx.x & 3;            // d-quarter: d0 = q*256
        const float* xb = x + ((size_t)b * ND + q * 256) * NP;
        float4 va[2], vb[2];
#pragma unroll
        for (int it = 0; it < 2; ++it) {
            const int u  = it * 256 + t;         // 0..511
            const int dh = u >> 2;               // d-pair 0..127
            const int p0 = (u & 3) * 4;
            va[it] = *reinterpret_cast<const float4*>(&xb[(size_t)(dh * 2)     * NP + p0]);
            vb[it] = *reinterpret_cast<const float4*>(&xb[(size_t)(dh * 2 + 1) * NP + p0]);
        }
#pragma unroll
        for (int it = 0; it < 2; ++it) {
            const int u  = it * 256 + t;
            const int dh = u >> 2;
            const int p0 = (u & 3) * 4;
            const float a0[4] = { va[it].x, va[it].y, va[it].z, va[it].w };
            const float a1[4] = { vb[it].x, vb[it].y, vb[it].z, vb[it].w };
#pragma unroll
            for (int k = 0; k < 4; ++k) {
                const uint packed = (uint)bf16_bits(a0[k]) | ((uint)bf16_bits(a1[k]) << 16);
                *reinterpret_cast<uint*>(&lds[p0 + k][dh * 2]) = packed;
            }
        }
        __syncthreads();
        const int p = t >> 4, j = t & 15;
        bf16* dst = xp + (size_t)p * (NB * ND) + (size_t)b * ND + q * 256;
#pragma unroll
        for (int it = 0; it < 2; ++it) {
            const int c = it * 16 + j;           // 0..31 chunks of 8 bf16
            *reinterpret_cast<bf16x8*>(&dst[c * 8]) =
                *reinterpret_cast<const bf16x8*>(&lds[p][c * 8]);
        }
    } else {
        // W convert: block covers 4096 consecutive floats (256 thr x 16)
        const size_t base = (size_t)(blockIdx.x - 4096) * 4096;
        float4 f[4];
#pragma unroll
        for (int k = 0; k < 4; ++k)
            f[k] = *reinterpret_cast<const float4*>(&w[base + (size_t)k * 1024 + t * 4]);
#pragma unroll
        for (int k = 0; k < 4; ++k) {
            alignas(8) bf16 tmp[4] = { __float2bfloat16(f[k].x), __float2bfloat16(f[k].y),
                                       __float2bfloat16(f[k].z), __float2bfloat16(f[k].w) };
            *reinterpret_cast<uint2*>(&wp[base + (size_t)k * 1024 + t * 4]) =
                *reinterpret_cast<const uint2*>(tmp);
        }
    }
}

// ---------- grouped GEMM: 256x256 tile, 8 waves, 32x32x16 MFMA, counted vmcnt ----------
// Per part p: y[p][b][o] = bf16( sum_d xp[p][b][d] * wp[p][o][d] )   (NO gelu here)
// Triple-buffered LDS; steady-state wait = vmcnt(4), never 0 until the tail.
// LDS rows are 64B (4 chunks of 16B); swizzle involution: chunk ^= (row>>1)&3,
// applied to the GLOBAL source (linear LDS dest, rule 21) and to ds_read.
__global__ __launch_bounds__(512, 2) void gemm8_kernel(const bf16* __restrict__ xp,
                                                       const bf16* __restrict__ wp,
                                                       bf16* __restrict__ y) {
    __shared__ bf16 As[3][256 * BKT];
    __shared__ bf16 Bs[3][256 * BKT];
    const int i = blockIdx.x;
    const int p    = ((i & 7) << 1) | ((i >> 3) & 1);   // part -> XCD i&7
    const int tile = i >> 4;                             // 0..15
    const int bt = (tile >> 2) * 256;
    const int ot = (tile & 3) * 256;
    const bf16* A  = xp + (size_t)p * NB * ND;   // [B][D]
    const bf16* Bm = wp + (size_t)p * ND * ND;   // [O][D]
    const int t = threadIdx.x;
    const int l = t & 63, w = t >> 6;            // 8 waves
    const int wr = w >> 2, wc = w & 3;           // 2(M) x 4(N): wave tile 128x64
    const int lr32 = l & 31, g2 = l >> 5;        // mfma row / k-half

    f32x16 acc[4][2] = {};                       // 4 m-tiles x 2 n-tiles of 32x32

    auto stage = [&](int buf, int kt, int q) {
        const int s   = ((q & 1) * 8 + w) * 64 + l;     // 16B slot 0..1023
        const int row = s >> 2;                          // 0..255
        const int cb  = (s & 3) ^ ((row >> 1) & 3);      // inverse-swizzled chunk
        const bf16* gsrc = (q < 2 ? A + (size_t)(bt + row) * ND
                                  : Bm + (size_t)(ot + row) * ND) + kt * BKT + cb * 8;
        bf16* ldst = (q < 2 ? &As[buf][((q & 1) * 8 + w) * 512]
                            : &Bs[buf][((q & 1) * 8 + w) * 512]);
        __builtin_amdgcn_global_load_lds((const __attribute__((address_space(1))) void*)gsrc,
                                         (__attribute__((address_space(3))) void*)ldst, 16, 0, 0);
    };
    auto readA = [&](int buf, int m, int s) -> bf16x8 {
        const int row  = wr * 128 + m * 32 + lr32;
        const int ch   = s * 2 + g2;
        const int slot = row * 4 + (ch ^ ((row >> 1) & 3));
        return *reinterpret_cast<const bf16x8*>(&As[buf][slot * 8]);
    };
    auto readB = [&](int buf, int n, int s) -> bf16x8 {
        const int row  = wc * 64 + n * 32 + lr32;
        const int ch   = s * 2 + g2;
        const int slot = row * 4 + (ch ^ ((row >> 1) & 3));
        return *reinterpret_cast<const bf16x8*>(&Bs[buf][slot * 8]);
    };

#pragma unroll
    for (int q = 0; q < 4; ++q) stage(0, 0, q);
#pragma unroll
    for (int q = 0; q < 4; ++q) stage(1, 1, q);
    asm volatile("s_waitcnt vmcnt(4)" ::: "memory");
    __builtin_amdgcn_s_barrier();
    __builtin_amdgcn_sched_barrier(0);

    int bufc = 0, bufs = 2;
#pragma unroll 1
    for (int kt = 0; kt < NKT; ++kt) {
        // ---- phase 0: k-step 0 frags ; stage A of tile kt+2 ----
        bf16x8 bfr[2], af[4];
#pragma unroll
        for (int n = 0; n < 2; ++n) bfr[n] = readB(bufc, n, 0);
#pragma unroll
        for (int m = 0; m < 4; ++m) af[m] = readA(bufc, m, 0);
        if (kt + 2 < NKT) { stage(bufs, kt + 2, 0); stage(bufs, kt + 2, 1); }
        __builtin_amdgcn_s_barrier();
        asm volatile("s_waitcnt lgkmcnt(0)" ::: "memory");
        __builtin_amdgcn_s_setprio(1);
#pragma unroll
        for (int m = 0; m < 4; ++m)
#pragma unroll
            for (int n = 0; n < 2; ++n)
                acc[m][n] = __builtin_amdgcn_mfma_f32_32x32x16_bf16(af[m], bfr[n], acc[m][n], 0, 0, 0);
        __builtin_amdgcn_s_setprio(0);
        __builtin_amdgcn_s_barrier();
        // ---- phase 1: k-step 1 frags ; stage B of tile kt+2 ----
#pragma unroll
        for (int n = 0; n < 2; ++n) bfr[n] = readB(bufc, n, 1);
#pragma unroll
        for (int m = 0; m < 4; ++m) af[m] = readA(bufc, m, 1);
        if (kt + 2 < NKT) { stage(bufs, kt + 2, 2); stage(bufs, kt + 2, 3); }
        __builtin_amdgcn_s_barrier();
        asm volatile("s_waitcnt lgkmcnt(0)" ::: "memory");
        __builtin_amdgcn_s_setprio(1);
#pragma unroll
        for (int m = 0; m < 4; ++m)
#pragma unroll
            for (int n = 0; n < 2; ++n)
                acc[m][n] = __builtin_amdgcn_mfma_f32_32x32x16_bf16(af[m], bfr[n], acc[m][n], 0, 0, 0);
        __builtin_amdgcn_s_setprio(0);
        if (kt < NKT - 1) {
            if (kt + 2 < NKT) asm volatile("s_waitcnt vmcnt(4)" ::: "memory");
            else              asm volatile("s_waitcnt vmcnt(0)" ::: "memory");
            __builtin_amdgcn_s_barrier();
            __builtin_amdgcn_sched_barrier(0);
        }
        bufc = (bufc == 2) ? 0 : bufc + 1;
        bufs = (bufs == 2) ? 0 : bufs + 1;
    }

    // epilogue: 32x32 C/D layout col = l&31, row = (reg&3) + 8*(reg>>2) + 4*(l>>5)
    bf16* yp = y + (size_t)p * NB * ND;
#pragma unroll
    for (int m = 0; m < 4; ++m) {
#pragma unroll
        for (int n = 0; n < 2; ++n) {
#pragma unroll
            for (int reg = 0; reg < 16; ++reg) {
                const int row = bt + wr * 128 + m * 32 + (reg & 3) + 8 * (reg >> 2) + 4 * g2;
                const int col = ot + wc * 64 + n * 32 + lr32;
                yp[(size_t)row * ND + col] = __float2bfloat16(acc[m][n][reg]);
            }
        }
    }
}

// ---------- y [P][B][O] bf16 (raw) -> out [B][O][P] f32 with exact GELU ----------
__global__ __launch_bounds__(256) void unpack_kernel(const bf16* __restrict__ y,
                                                     float* __restrict__ out) {
    const size_t gidx = (size_t)blockIdx.x * 256 + threadIdx.x;  // (b,o) index
    const size_t o = gidx & 1023;
    const size_t b = gidx >> 10;
    const bf16* yb = y + b * (size_t)ND + o;
    float v[16];
#pragma unroll
    for (int p = 0; p < 16; ++p)
        v[p] = gelu_exact(__bfloat162float(yb[(size_t)p * (NB * ND)]));
    float4* dst = reinterpret_cast<float4*>(out + gidx * NP);
#pragma unroll
    for (int q = 0; q < 4; ++q)
        dst[q] = make_float4(v[q * 4], v[q * 4 + 1], v[q * 4 + 2], v[q * 4 + 3]);
}

// ---------- fallback: pure-f32 tiled GEMM (tiny ws) ----------
__global__ __launch_bounds__(256) void fallback_kernel(const float* __restrict__ x,
                                                       const float* __restrict__ w,
                                                       float* __restrict__ out) {
    __shared__ float As[64][17];
    __shared__ float Bs[64][17];
    const int p = blockIdx.z, bt = blockIdx.y * 64, ot = blockIdx.x * 64;
    const int t = threadIdx.x;
    const int tx = t & 15, ty = t >> 4;
    float acc[4][4] = {};
    for (int k0 = 0; k0 < ND; k0 += 16) {
        __syncthreads();
#pragma unroll
        for (int i = 0; i < 4; ++i) {
            const int idx = i * 256 + t;
            const int r = idx >> 4, k = idx & 15;
            As[r][k] = x[((size_t)(bt + r) * ND + k0 + k) * NP + p];
            Bs[r][k] = w[(size_t)p * ND * ND + (size_t)(ot + r) * ND + k0 + k];
        }
        __syncthreads();
#pragma unroll
        for (int k = 0; k < 16; ++k) {
            float a[4], bb[4];
#pragma unroll
            for (int i = 0; i < 4; ++i) a[i] = As[ty * 4 + i][k];
#pragma unroll
            for (int j = 0; j < 4; ++j) bb[j] = Bs[tx * 4 + j][k];
#pragma unroll
            for (int i = 0; i < 4; ++i)
#pragma unroll
                for (int j = 0; j < 4; ++j) acc[i][j] += a[i] * bb[j];
        }
    }
#pragma unroll
    for (int i = 0; i < 4; ++i)
#pragma unroll
        for (int j = 0; j < 4; ++j)
            out[((size_t)(bt + ty * 4 + i) * ND + (ot + tx * 4 + j)) * NP + p] =
                gelu_exact(acc[i][j]);
}

extern "C" void kernel_launch(void* const* d_in, const int* in_sizes, int n_in,
                              void* d_out, int out_size, void* d_ws, size_t ws_size,
                              hipStream_t stream) {
    const float* x = (const float*)d_in[0];
    const float* w = (const float*)d_in[1];
    float* out = (float*)d_out;

    const size_t nElem     = (size_t)NP * NB * ND;            // 16M
    const size_t packBytes = nElem * sizeof(bf16) * 2;        // 64 MiB (xp + wp)
    const size_t yBytes    = nElem * sizeof(bf16);            // 32 MiB (bf16 y)

    if (ws_size >= packBytes + yBytes) {
        bf16* xp = (bf16*)d_ws;
        bf16* wp = xp + nElem;
        bf16* y  = (bf16*)((char*)d_ws + packBytes);
        pack_kernel<<<8192, 256, 0, stream>>>(x, w, xp, wp);
        gemm8_kernel<<<256, 512, 0, stream>>>(xp, wp, y);
        unpack_kernel<<<(int)(NB * ND / 256), 256, 0, stream>>>(y, out);
    } else {
        fallback_kernel<<<dim3(16, 16, 16), 256, 0, stream>>>(x, w, out);
    }
}